// Round 3
// baseline (96.353 us; speedup 1.0000x reference)
//
#include <hip/hip_runtime.h>
#include <hip/hip_bf16.h>
#include <math.h>

// SUB_Independent_Loss — contrastive pairwise loss, single f32 scalar out.
// N1 = N2 = 256, D = 1024.
//
// 3 launches: gemm_mfma (inline f32->bf16 convert) -> loss (per-block
// partials, no init needed) -> finalize (reduce 1024 partials).
//
// ws layout:
//   [0)       sims: 3 * 256*256 f32 (sim12, sim11, sim22) = 786432 B
//   [786432)  pLoss: 1024 f32                             = 4096 B
//   [790528)  pCnt:  1024 i32                             = 4096 B

#define NN 256
#define DD 1024

typedef __attribute__((ext_vector_type(8))) short short8;   // 8 bf16 = 4 VGPRs
typedef __attribute__((ext_vector_type(4))) float f32x4;

__device__ __forceinline__ unsigned short f32_to_bf16_rne(float x) {
    unsigned int u = __float_as_uint(x);
    u += 0x7fffu + ((u >> 16) & 1u);     // RNE; inputs finite
    return (unsigned short)(u >> 16);
}

__device__ __forceinline__ short8 cvt8(float4 a, float4 b) {
    short8 r;
    r[0] = (short)f32_to_bf16_rne(a.x);
    r[1] = (short)f32_to_bf16_rne(a.y);
    r[2] = (short)f32_to_bf16_rne(a.z);
    r[3] = (short)f32_to_bf16_rne(a.w);
    r[4] = (short)f32_to_bf16_rne(b.x);
    r[5] = (short)f32_to_bf16_rne(b.y);
    r[6] = (short)f32_to_bf16_rne(b.z);
    r[7] = (short)f32_to_bf16_rne(b.w);
    return r;
}

// ---------------------------------------------------------------------------
// Kernel 1: three NT GEMMs via bf16 MFMA, converting f32->bf16 inline.
// One wave per 16x16 output tile, full K=1024 (32 mfma). 768 waves ->
// 192 blocks x 4 waves. Everything L2-resident.
// A-operand layout: lane holds A[m=lane&15][k=(lane>>4)*8+j], j=0..7 (m89).
// C/D layout: col = lane&15, row = (lane>>4)*4 + reg (m89).
// ---------------------------------------------------------------------------
__global__ __launch_bounds__(256) void gemm_mfma(
        const float* __restrict__ f1, const float* __restrict__ f2,
        float* __restrict__ sims) {
    const int gwave = blockIdx.x * 4 + (threadIdx.x >> 6);  // 0..767
    const int m = gwave >> 8;                               // matrix 0..2
    const int t = gwave & 255;                              // tile 0..255
    const int tr = t >> 4, tc = t & 15;
    const float* A  = (m == 2) ? f2 : f1;
    const float* Bm = (m == 0) ? f2 : ((m == 1) ? f1 : f2);
    float* C = sims + m * (NN * NN);

    const int lane = threadIdx.x & 63;
    const int r = lane & 15;
    const int quad = lane >> 4;

    const float* aptr = A  + (tr * 16 + r) * DD + quad * 8;
    const float* bptr = Bm + (tc * 16 + r) * DD + quad * 8;

    f32x4 acc = {0.f, 0.f, 0.f, 0.f};
#pragma unroll 4
    for (int k0 = 0; k0 < DD; k0 += 32) {
        float4 a0 = *(const float4*)(aptr + k0);
        float4 a1 = *(const float4*)(aptr + k0 + 4);
        float4 b0 = *(const float4*)(bptr + k0);
        float4 b1 = *(const float4*)(bptr + k0 + 4);
        short8 af = cvt8(a0, a1);
        short8 bf = cvt8(b0, b1);
        acc = __builtin_amdgcn_mfma_f32_16x16x32_bf16(af, bf, acc, 0, 0, 0);
    }
    const int row0 = tr * 16 + quad * 4;
    const int col = tc * 16 + r;
#pragma unroll
    for (int rr = 0; rr < 4; rr++) {
        C[(row0 + rr) * NN + col] = acc[rr];
    }
}

// ---------------------------------------------------------------------------
// Kernel 2: loss. grid (256 rows, 4 calls), 256 threads/block. Writes
// per-block partials ALWAYS (so no init pass is needed).
// call 0: sim12 row i / mc row i / sel1;  call 1: sim12 col i / mc col i / sel2
// call 2: sim11 row i / m1 row i / sel1;  call 3: sim22 row i / m2 row i / sel2
// sel decode: mask_sents may be bool-bytes or int32. int32 0/1 data has
// all-zero bytes at i%4!=0 in its first 256 B; random bool data has ~96
// nonzero ones there (misdetect prob ~2^-192). Each block probes inline.
// Ballot-compact pos/neg values (pre-scaled by log2e) into LDS; each thread
// holds one neg in a register (pad -1e30 => exact 0), loops over pos 4-wide
// via ds_read_b128 broadcast (pos list padded with +1e30 => exact 0).
// softplus(x)/ln2 = max(x2,0) + log2(1+2^-|x2|).
// ---------------------------------------------------------------------------
__global__ __launch_bounds__(256) void loss_kernel(
        const float* __restrict__ sims,
        const int* __restrict__ mc,
        const int* __restrict__ m1,
        const int* __restrict__ m2,
        const void* ms1, const void* ms2,
        float* __restrict__ pLoss, int* __restrict__ pCnt) {
    const int i = blockIdx.x;
    const int c = blockIdx.y;
    const int tid = threadIdx.x;
    const int bid = c * NN + i;
    const int lane = tid & 63;
    const int w = tid >> 6;

    const float* sim12 = sims;
    const float* sim11 = sims + NN * NN;
    const float* sim22 = sims + 2 * NN * NN;

    __shared__ alignas(16) float sPos[NN + 4];
    __shared__ float sNeg[NN];
    __shared__ int wcnt[4];
    __shared__ float red[4];
    __shared__ int detFlag;

    // --- sel decode (block-local bool/int32 probe) ---
    const void* ms = (c == 1 || c == 3) ? ms2 : ms1;
    if (tid == 0) detFlag = 0;
    __syncthreads();
    const unsigned char* mb = (const unsigned char*)ms;
    bool nzb = ((tid & 3) != 0) && (mb[tid] != 0);
    unsigned long long det = __ballot(nzb);
    if (lane == 0 && det) atomicOr(&detFlag, 1);

    float simv;
    int maskv;
    if (c == 0) {
        simv = sim12[i * NN + tid]; maskv = mc[i * NN + tid];
    } else if (c == 1) {
        simv = sim12[tid * NN + i]; maskv = mc[tid * NN + i];
    } else if (c == 2) {
        simv = sim11[i * NN + tid]; maskv = m1[i * NN + tid];
    } else {
        simv = sim22[i * NN + tid]; maskv = m2[i * NN + tid];
    }
    __syncthreads();
    const bool isBool = (detFlag != 0);
    const float sel = isBool ? (mb[i] ? 1.0f : 0.0f)
                             : (float)((const int*)ms)[i];
    if (sel == 0.0f) {                       // block-uniform
        if (tid == 0) { pLoss[bid] = 0.0f; pCnt[bid] = 0; }
        return;
    }

    const float LOG2E = 1.4426950408889634f;
    const float LN2   = 0.6931471805599453f;

    // --- ballot compaction ---
    const bool pos = (maskv != 0);
    unsigned long long bal = __ballot(pos);
    if (lane == 0) wcnt[w] = __popcll(bal);
    __syncthreads();

    int posBase = 0, np_ = 0;
#pragma unroll
    for (int q = 0; q < 4; q++) {
        int v = wcnt[q];
        if (q < w) posBase += v;
        np_ += v;
    }
    const int nn_ = NN - np_;

    const unsigned long long ltmask = (1ull << lane) - 1ull;
    const int pp = __popcll(bal & ltmask);
    const float tval = simv * LOG2E;
    if (pos) sPos[posBase + pp] = tval;
    else     sNeg[(w * 64 - posBase) + (lane - pp)] = tval;
    if (tid < 4) sPos[np_ + tid] = 1e30f;    // pad => exact 0 contribution
    __syncthreads();

    if (np_ == 0 || nn_ == 0) {              // block-uniform
        if (tid == 0) { pLoss[bid] = 0.0f; pCnt[bid] = 0; }
        return;
    }

    const int np4 = (np_ + 3) & ~3;
    const float tn = (tid < nn_) ? sNeg[tid] : -1e30f;  // pad => 0
    float accL0 = 0.f, accM0 = 0.f, accL1 = 0.f, accM1 = 0.f;
    for (int jj = 0; jj < np4; jj += 4) {
        float4 sp = *(const float4*)&sPos[jj];   // ds_read_b128 broadcast
        float x0 = tn - sp.x;
        float x1 = tn - sp.y;
        float x2 = tn - sp.z;
        float x3 = tn - sp.w;
        accL0 += __builtin_amdgcn_logf(1.0f + __builtin_amdgcn_exp2f(-fabsf(x0)));
        accM0 += fmaxf(x0, 0.0f);
        accL1 += __builtin_amdgcn_logf(1.0f + __builtin_amdgcn_exp2f(-fabsf(x1)));
        accM1 += fmaxf(x1, 0.0f);
        accL0 += __builtin_amdgcn_logf(1.0f + __builtin_amdgcn_exp2f(-fabsf(x2)));
        accM0 += fmaxf(x2, 0.0f);
        accL1 += __builtin_amdgcn_logf(1.0f + __builtin_amdgcn_exp2f(-fabsf(x3)));
        accM1 += fmaxf(x3, 0.0f);
    }
    float local = ((accL0 + accL1) + (accM0 + accM1)) * LN2;

    // block reduction (4 waves of 64)
#pragma unroll
    for (int off = 32; off > 0; off >>= 1) local += __shfl_down(local, off, 64);
    if (lane == 0) red[w] = local;
    __syncthreads();
    if (tid == 0) {
        pLoss[bid] = red[0] + red[1] + red[2] + red[3];
        pCnt[bid] = np_ * nn_;
    }
}

// ---------------------------------------------------------------------------
// Kernel 3: reduce 1024 partials -> scalar.
// ---------------------------------------------------------------------------
__global__ __launch_bounds__(256) void finalize_kernel(
        const float* __restrict__ pLoss, const int* __restrict__ pCnt,
        float* __restrict__ out) {
    const int tid = threadIdx.x;
    const int lane = tid & 63;
    double s = 0.0;
    long long cnt = 0;
#pragma unroll
    for (int q = 0; q < 4; q++) {
        int k = tid + q * 256;
        s += (double)pLoss[k];
        cnt += (long long)pCnt[k];
    }
#pragma unroll
    for (int off = 32; off > 0; off >>= 1) {
        s += __shfl_down(s, off, 64);
        cnt += __shfl_down(cnt, off, 64);
    }
    __shared__ double rs[4];
    __shared__ long long rc[4];
    if (lane == 0) { rs[tid >> 6] = s; rc[tid >> 6] = cnt; }
    __syncthreads();
    if (tid == 0) {
        double loss = rs[0] + rs[1] + rs[2] + rs[3];
        long long p = rc[0] + rc[1] + rc[2] + rc[3];
        out[0] = (float)((p > 0) ? loss / (double)p : loss);
    }
}

extern "C" void kernel_launch(void* const* d_in, const int* in_sizes, int n_in,
                              void* d_out, int out_size, void* d_ws, size_t ws_size,
                              hipStream_t stream) {
    const float* f1 = (const float*)d_in[0];
    const float* f2 = (const float*)d_in[1];
    const int* mc = (const int*)d_in[2];
    const int* m1 = (const int*)d_in[3];
    const int* m2 = (const int*)d_in[4];
    const void* ms1 = d_in[5];
    const void* ms2 = d_in[6];

    char* ws = (char*)d_ws;
    float* sims  = (float*)ws;             // 786432 B
    float* pLoss = (float*)(ws + 786432);  // 4096 B
    int*   pCnt  = (int*)(ws + 790528);    // 4096 B

    gemm_mfma<<<192, 256, 0, stream>>>(f1, f2, sims);
    loss_kernel<<<dim3(256, 4), 256, 0, stream>>>(sims, mc, m1, m2, ms1, ms2,
                                                  pLoss, pCnt);
    finalize_kernel<<<1, 256, 0, stream>>>(pLoss, pCnt, (float*)d_out);
}